// Round 6
// baseline (7051.469 us; speedup 1.0000x reference)
//
#include <hip/hip_runtime.h>
#include <math.h>

#define Bq 4
#define Mq 500
#define Nq 500
#define Cq 91

// ---------------------------------------------------------------------------
// Phase 1: cost[b,i,j] = 0.5*||center2_i - center1_j||_2
//                      + 0.5*max_c |sigmoid(l2[i,c]) - sigmoid(l1[j,c])|
// ---------------------------------------------------------------------------
__device__ __forceinline__ float sigmoidf_(float x) {
    return 1.0f / (1.0f + expf(-x));
}

__global__ __launch_bounds__(256) void cost_kernel(
    const float* __restrict__ p1_boxes, const float* __restrict__ p1_logits,
    const float* __restrict__ p2_boxes, const float* __restrict__ p2_logits,
    float* __restrict__ cost)
{
    __shared__ float s2t[16][Cq + 1];   // stride 92 -> 2-way bank alias (free)
    __shared__ float s1t[16][Cq + 1];
    __shared__ float b2x[16], b2y[16], b1x[16], b1y[16];
    const int b  = blockIdx.z;
    const int i0 = blockIdx.y * 16;
    const int j0 = blockIdx.x * 16;
    const int tid = threadIdx.x;

    for (int t = tid; t < 16 * Cq; t += 256) {
        const int r = t / Cq, c = t - r * Cq;
        const int i = min(i0 + r, Mq - 1);
        const int j = min(j0 + r, Nq - 1);
        s2t[r][c] = sigmoidf_(p2_logits[((size_t)b * Mq + i) * Cq + c]);
        s1t[r][c] = sigmoidf_(p1_logits[((size_t)b * Nq + j) * Cq + c]);
    }
    if (tid < 16) {
        const int i = min(i0 + tid, Mq - 1);
        const int j = min(j0 + tid, Nq - 1);
        b2x[tid] = p2_boxes[((size_t)b * Mq + i) * 4 + 0];
        b2y[tid] = p2_boxes[((size_t)b * Mq + i) * 4 + 1];
        b1x[tid] = p1_boxes[((size_t)b * Nq + j) * 4 + 0];
        b1y[tid] = p1_boxes[((size_t)b * Nq + j) * 4 + 1];
    }
    __syncthreads();

    const int ty = tid >> 4, tx = tid & 15;
    const int i = i0 + ty, j = j0 + tx;
    if (i < Mq && j < Nq) {
        float mx = 0.0f;
        #pragma unroll 7
        for (int c = 0; c < Cq; ++c)
            mx = fmaxf(mx, fabsf(s2t[ty][c] - s1t[tx][c]));
        const float dx = b2x[ty] - b1x[tx];
        const float dy = b2y[ty] - b1y[tx];
        const float cd = sqrtf(dx * dx + dy * dy);
        cost[((size_t)b * Mq + i) * Nq + j] = 0.5f * cd + 0.5f * mx;
    }
}

// ---------------------------------------------------------------------------
// Phase 1.5: column reduction. v0[b][j] = min_i cost[b][i][j], amin = argmin.
// ---------------------------------------------------------------------------
__global__ __launch_bounds__(256) void colred_kernel(
    const float* __restrict__ cost, float* __restrict__ v0, int* __restrict__ amin)
{
    const int j = blockIdx.x * 256 + threadIdx.x;
    const int b = blockIdx.y;
    if (j >= Nq) return;
    const float* __restrict__ cb = cost + (size_t)b * Mq * Nq;
    float best = INFINITY;
    int bi = 0;
    #pragma unroll 4
    for (int i = 0; i < Mq; ++i) {
        const float c = cb[(size_t)i * Nq + j];
        if (c < best) { best = c; bi = i; }
    }
    v0[b * Nq + j] = best;
    amin[b * Nq + j] = bi;
}

// ---------------------------------------------------------------------------
// u64 lexicographic-min DPP tree over 64 lanes (row_shr 1/2/4/8 +
// row_bcast15/31 into lane 63, then readlane-broadcast). Invalid DPP source
// lanes receive all-ones (never win). Verified correct in R5 (absmax 0.0).
// ---------------------------------------------------------------------------
template<int CTRL>
__device__ __forceinline__ unsigned long long dppmin_u64_(unsigned long long x) {
    const unsigned lo = (unsigned)__builtin_amdgcn_update_dpp(
        (int)0xFFFFFFFFu, (int)(unsigned)x, CTRL, 0xF, 0xF, false);
    const unsigned hi = (unsigned)__builtin_amdgcn_update_dpp(
        (int)0xFFFFFFFFu, (int)(unsigned)(x >> 32), CTRL, 0xF, 0xF, false);
    const unsigned long long o = ((unsigned long long)hi << 32) | lo;
    return o < x ? o : x;
}
__device__ __forceinline__ unsigned long long wave_min_u64_(unsigned long long x) {
    x = dppmin_u64_<0x111>(x);
    x = dppmin_u64_<0x112>(x);
    x = dppmin_u64_<0x114>(x);
    x = dppmin_u64_<0x118>(x);
    x = dppmin_u64_<0x142>(x);
    x = dppmin_u64_<0x143>(x);
    const unsigned lo = (unsigned)__builtin_amdgcn_readlane((int)(unsigned)x, 63);
    const unsigned hi = (unsigned)__builtin_amdgcn_readlane((int)(unsigned)(x >> 32), 63);
    return ((unsigned long long)hi << 32) | lo;
}

// ---------------------------------------------------------------------------
// Phase 2: exact successive-shortest-path LAP (same unique optimum as the
// reference's LAPJV). One block = one batch, ONE wave. BLOCKED column
// ownership: lane L owns j in {4L..4L+3} u {256+4L..256+4L+3}. Row loads are
// 2x global_load_dwordx4.
//
// Hot-loop structure (ZERO multi-address LDS per pop):
//   key[k] = (f32bits(shortest)<<19) | (j<<10) | (row4col[j]+1)
// with row4col carried in per-lane REGISTERS (low19_r, refreshed per
// augment). The u64 DPP argmin tree then yields min_val, jst, AND the next
// row i in one reduction — the row load issues immediately, and the
// wave-uniform (broadcast) u_lds[i] read hides under it.
// Key order = (value, j) lexicographic => np.argmin lowest-j tie-break.
// ---------------------------------------------------------------------------
__global__ __launch_bounds__(64) void lsa_kernel(
    const float* __restrict__ cost, const float* __restrict__ v0,
    const int* __restrict__ amin, int* __restrict__ mapping)
{
    constexpr int n = Nq;  // 500
    __shared__ float u_lds[512];
    __shared__ float shortest_lds[512];
    __shared__ int   path_lds[512];
    __shared__ int   row4col_lds[512];
    __shared__ int   col4row_lds[512];

    const int lane = threadIdx.x;
    const int b = blockIdx.x;
    const float* __restrict__ cb = cost + (size_t)b * n * n;

    const int jb0 = lane << 2;                    // cols 4L..4L+3
    const int jb1 = 256 + (lane << 2);            // cols 256+4L.. (lane<61)
    const int jb1c = 256 + (min(lane, 60) << 2);  // clamped load base
    const unsigned init_mask = (lane < 61) ? 0xFFu : 0x0Fu;

    float v_r[8], short_r[8];
    int path_r[8];
    unsigned low19_r[8];   // (j<<10) | (row4col[j]+1), per owned column

    // --- init: duals from column reduction, greedy matching on tight edges ---
    #pragma unroll
    for (int k = 0; k < 8; ++k) {
        const int j = (k < 4) ? (jb0 + k) : (jb1 + k - 4);
        v_r[k] = (init_mask & (1u << k)) ? v0[b * n + j] : 0.0f;
        short_r[k] = INFINITY;
        path_r[k] = -1;
    }
    for (int t = lane; t < n; t += 64)
        path_lds[t] = amin[b * n + t];            // stash argmins for lane0
    for (int t = lane; t < 512; t += 64) {
        u_lds[t] = 0.0f; row4col_lds[t] = -1; col4row_lds[t] = -1;
    }
    __syncthreads();
    if (lane == 0) {
        for (int j = 0; j < n; ++j) {
            const int i0 = path_lds[j];
            if (col4row_lds[i0] < 0) { col4row_lds[i0] = j; row4col_lds[j] = i0; }
        }
    }
    __syncthreads();
    #pragma unroll
    for (int k = 0; k < 8; ++k) {
        const int j = (k < 4) ? (jb0 + k) : (jb1 + k - 4);
        const int rc = (init_mask & (1u << k)) ? row4col_lds[j] : -1;
        low19_r[k] = ((unsigned)j << 10) | (unsigned)(rc + 1);
    }
    for (int t = lane; t < n; t += 64)
        path_lds[t] = -1;
    unsigned rem = init_mask;
    unsigned sr_mask = 0;
    __syncthreads();

    // --- successive shortest paths over free rows ---
    for (int cur_row = 0; cur_row < n; ++cur_row) {
        if (col4row_lds[cur_row] >= 0) continue;   // wave-uniform

        int sink_j = -1;
        int i = cur_row;
        float min_val = 0.0f;
        float a = -u_lds[cur_row];                  // a = min_val - u[i]
        const float* __restrict__ crow = cb + (size_t)i * n;

        for (int pops = 0; pops < n; ++pops) {
            if ((i & 63) == lane) sr_mask |= 1u << (i >> 6);

            // two 16B coalesced row loads; t_k fills the load shadow
            const float4 c0 = *(const float4*)(crow + jb0);
            const float4 c1 = *(const float4*)(crow + jb1c);
            float t_r[8];
            #pragma unroll
            for (int k = 0; k < 8; ++k) t_r[k] = a - v_r[k];
            const float cv[8] = {c0.x, c0.y, c0.z, c0.w, c1.x, c1.y, c1.z, c1.w};

            float lmin = INFINITY;
            unsigned lsel = 0x7FFFFu;
            #pragma unroll
            for (int k = 0; k < 8; ++k) {
                if (rem & (1u << k)) {
                    const float r = fmaxf(cv[k] + t_r[k], 0.0f);
                    if (r < short_r[k]) { short_r[k] = r; path_r[k] = i; }
                    // k ascending => ascending j within lane: '<' keeps lowest j
                    if (short_r[k] < lmin) { lmin = short_r[k]; lsel = low19_r[k]; }
                }
            }

            const unsigned long long key =
                ((unsigned long long)__float_as_uint(lmin) << 19) | lsel;
            const unsigned long long win = wave_min_u64_(key);

            const unsigned lo  = (unsigned)win;
            const unsigned rc1 = lo & 0x3FFu;
            const unsigned jst = (lo >> 10) & 0x1FFu;
            min_val = __uint_as_float((unsigned)(win >> 19));

            const int owner = (int)((jst & 255u) >> 2);
            if (owner == lane) rem &= ~(1u << ((jst & 3u) + ((jst >> 8) << 2)));

            if (rc1 == 0u) { sink_j = (int)jst; break; }
            i = (int)rc1 - 1;
            crow = cb + (size_t)i * n;
            a = min_val - u_lds[i];   // broadcast LDS read, hides under row load
        }

        if (sink_j >= 0) {
            // publish shortest/path (blocked mapping; guard k>=4 for lane>=61)
            #pragma unroll
            for (int k = 0; k < 8; ++k) {
                if (init_mask & (1u << k)) {
                    const int j = (k < 4) ? (jb0 + k) : (jb1 + k - 4);
                    shortest_lds[j] = short_r[k];
                    path_lds[j] = path_r[k];
                }
            }
            __syncthreads();

            // dual updates (col4row read BEFORE augmentation, per reference);
            // row side uses strided ownership (sr_mask bit k <-> row lane+64k)
            #pragma unroll
            for (int k = 0; k < 8; ++k) {
                const int t = lane + (k << 6);
                if (t < n && (sr_mask & (1u << k))) {
                    if (t == cur_row) u_lds[t] += min_val;
                    else              u_lds[t] += min_val - shortest_lds[col4row_lds[t]];
                }
            }
            const unsigned scanned = init_mask & ~rem;
            #pragma unroll
            for (int k = 0; k < 8; ++k)
                if (scanned & (1u << k)) v_r[k] -= min_val - short_r[k];
            __syncthreads();

            if (lane == 0) {   // augment alternating path
                int j = sink_j;
                for (;;) {
                    const int ii = path_lds[j];
                    row4col_lds[j] = ii;
                    const int tmp = col4row_lds[ii];
                    col4row_lds[ii] = j;
                    j = tmp;
                    if (ii == cur_row) break;
                }
            }
            __syncthreads();
        }

        // refresh per-lane row4col payloads; reset per-row state
        #pragma unroll
        for (int k = 0; k < 8; ++k) {
            const int j = (k < 4) ? (jb0 + k) : (jb1 + k - 4);
            const int rc = (init_mask & (1u << k)) ? row4col_lds[j] : -1;
            low19_r[k] = ((unsigned)j << 10) | (unsigned)(rc + 1);
            short_r[k] = INFINITY;
            path_r[k] = -1;
        }
        rem = init_mask;
        sr_mask = 0;
        __syncthreads();
    }

    for (int t = lane; t < n; t += 64)
        mapping[b * n + t] = col4row_lds[t];
}

// ---------------------------------------------------------------------------
// Phase 3: extrapolation (square problem => every row assigned; -1 guarded).
// ---------------------------------------------------------------------------
__global__ __launch_bounds__(256) void extrap_boxes_kernel(
    const float* __restrict__ p1_boxes, const float* __restrict__ p2_boxes,
    const float* __restrict__ toffs, const int* __restrict__ mapping,
    float* __restrict__ out_boxes)
{
    const int idx = blockIdx.x * blockDim.x + threadIdx.x;  // b*Mq + i
    if (idx >= Bq * Mq) return;
    const int b = idx / Mq;
    const float t0 = toffs[b * 3 + 0], t1 = toffs[b * 3 + 1], t2 = toffs[b * 3 + 2];
    const float factor = (t2 - t1) / (t1 - t0);
    const int m = mapping[idx];
    const float4 p2 = ((const float4*)p2_boxes)[idx];
    const float4 p1 = (m >= 0) ? ((const float4*)p1_boxes)[b * Nq + m] : p2;
    float4 o;
    o.x = p2.x + (p2.x - p1.x) * factor;
    o.y = p2.y + (p2.y - p1.y) * factor;
    o.z = fmaxf(p2.z + (p2.z - p1.z) * factor, 0.0f);
    o.w = fmaxf(p2.w + (p2.w - p1.w) * factor, 0.0f);
    ((float4*)out_boxes)[idx] = o;
}

__global__ __launch_bounds__(256) void extrap_logits_kernel(
    const float* __restrict__ p1_logits, const float* __restrict__ p2_logits,
    const int* __restrict__ mapping, float* __restrict__ out_logits)
{
    const int idx = blockIdx.x * blockDim.x + threadIdx.x;  // (b*Mq + i)*Cq + c
    if (idx >= Bq * Mq * Cq) return;
    const int c = idx % Cq;
    const int bi = idx / Cq;
    const int b = bi / Mq;
    const int m = mapping[bi];
    const float corr = (m >= 0) ? p1_logits[((size_t)b * Nq + m) * Cq + c] : 0.0f;
    out_logits[idx] = 0.5f * (p2_logits[idx] + corr);
}

// ---------------------------------------------------------------------------
extern "C" void kernel_launch(void* const* d_in, const int* in_sizes, int n_in,
                              void* d_out, int out_size, void* d_ws, size_t ws_size,
                              hipStream_t stream) {
    const float* p1_boxes  = (const float*)d_in[0];  // (B,N,4)
    const float* p1_logits = (const float*)d_in[1];  // (B,N,C)
    const float* p2_boxes  = (const float*)d_in[2];  // (B,M,4)
    const float* p2_logits = (const float*)d_in[3];  // (B,M,C)
    const float* toffs     = (const float*)d_in[4];  // (B,3)
    float* out = (float*)d_out;                      // boxes3 ++ logits3

    char* ws = (char*)d_ws;
    float* cost    = (float*)ws;                                   // 4 MB
    int*   mapping = (int*)  (ws + 4000000);                       // 8 KB
    float* v0      = (float*)(ws + 4008000);                       // 8 KB
    int*   amin    = (int*)  (ws + 4016000);                       // 8 KB

    dim3 cgrid((Nq + 15) / 16, (Mq + 15) / 16, Bq);
    cost_kernel<<<cgrid, 256, 0, stream>>>(p1_boxes, p1_logits, p2_boxes, p2_logits, cost);

    colred_kernel<<<dim3(2, Bq), 256, 0, stream>>>(cost, v0, amin);

    lsa_kernel<<<Bq, 64, 0, stream>>>(cost, v0, amin, mapping);

    extrap_boxes_kernel<<<(Bq * Mq + 255) / 256, 256, 0, stream>>>(
        p1_boxes, p2_boxes, toffs, mapping, out);
    extrap_logits_kernel<<<(Bq * Mq * Cq + 255) / 256, 256, 0, stream>>>(
        p1_logits, p2_logits, mapping, out + Bq * Mq * 4);
}

// Round 7
// 4985.225 us; speedup vs baseline: 1.4145x; 1.4145x over previous
//
#include <hip/hip_runtime.h>
#include <math.h>

#define Bq 4
#define Mq 500
#define Nq 500
#define Cq 91

// ---------------------------------------------------------------------------
// Phase 1: cost[b,i,j] = 0.5*||center2_i - center1_j||_2
//                      + 0.5*max_c |sigmoid(l2[i,c]) - sigmoid(l1[j,c])|
// ---------------------------------------------------------------------------
__device__ __forceinline__ float sigmoidf_(float x) {
    return 1.0f / (1.0f + expf(-x));
}

__global__ __launch_bounds__(256) void cost_kernel(
    const float* __restrict__ p1_boxes, const float* __restrict__ p1_logits,
    const float* __restrict__ p2_boxes, const float* __restrict__ p2_logits,
    float* __restrict__ cost)
{
    __shared__ float s2t[16][Cq + 1];   // stride 92 -> 2-way bank alias (free)
    __shared__ float s1t[16][Cq + 1];
    __shared__ float b2x[16], b2y[16], b1x[16], b1y[16];
    const int b  = blockIdx.z;
    const int i0 = blockIdx.y * 16;
    const int j0 = blockIdx.x * 16;
    const int tid = threadIdx.x;

    for (int t = tid; t < 16 * Cq; t += 256) {
        const int r = t / Cq, c = t - r * Cq;
        const int i = min(i0 + r, Mq - 1);
        const int j = min(j0 + r, Nq - 1);
        s2t[r][c] = sigmoidf_(p2_logits[((size_t)b * Mq + i) * Cq + c]);
        s1t[r][c] = sigmoidf_(p1_logits[((size_t)b * Nq + j) * Cq + c]);
    }
    if (tid < 16) {
        const int i = min(i0 + tid, Mq - 1);
        const int j = min(j0 + tid, Nq - 1);
        b2x[tid] = p2_boxes[((size_t)b * Mq + i) * 4 + 0];
        b2y[tid] = p2_boxes[((size_t)b * Mq + i) * 4 + 1];
        b1x[tid] = p1_boxes[((size_t)b * Nq + j) * 4 + 0];
        b1y[tid] = p1_boxes[((size_t)b * Nq + j) * 4 + 1];
    }
    __syncthreads();

    const int ty = tid >> 4, tx = tid & 15;
    const int i = i0 + ty, j = j0 + tx;
    if (i < Mq && j < Nq) {
        float mx = 0.0f;
        #pragma unroll 7
        for (int c = 0; c < Cq; ++c)
            mx = fmaxf(mx, fabsf(s2t[ty][c] - s1t[tx][c]));
        const float dx = b2x[ty] - b1x[tx];
        const float dy = b2y[ty] - b1y[tx];
        const float cd = sqrtf(dx * dx + dy * dy);
        cost[((size_t)b * Mq + i) * Nq + j] = 0.5f * cd + 0.5f * mx;
    }
}

// ---------------------------------------------------------------------------
// Phase 1.5: column reduction. v0[b][j] = min_i cost[b][i][j], amin = argmin.
// ---------------------------------------------------------------------------
__global__ __launch_bounds__(256) void colred_kernel(
    const float* __restrict__ cost, float* __restrict__ v0, int* __restrict__ amin)
{
    const int j = blockIdx.x * 256 + threadIdx.x;
    const int b = blockIdx.y;
    if (j >= Nq) return;
    const float* __restrict__ cb = cost + (size_t)b * Mq * Nq;
    float best = INFINITY;
    int bi = 0;
    #pragma unroll 4
    for (int i = 0; i < Mq; ++i) {
        const float c = cb[(size_t)i * Nq + j];
        if (c < best) { best = c; bi = i; }
    }
    v0[b * Nq + j] = best;
    amin[b * Nq + j] = bi;
}

// ---------------------------------------------------------------------------
// Fused-DPP wave64 min reductions (VALU-only; v_min_*_dpp single instr).
// row_shr 1/2/4/8 + row_bcast15/31 into lane 63; readlane broadcasts.
// Proven correct in R3 (absmax 0.0).
// ---------------------------------------------------------------------------
template<int CTRL>
__device__ __forceinline__ float dppmin_f32_(float x) {
    const int moved = __builtin_amdgcn_update_dpp(
        0x7F800000, __float_as_int(x), CTRL, 0xF, 0xF, false);
    return fminf(x, __int_as_float(moved));
}
__device__ __forceinline__ float wave_min_f32_(float x) {
    x = dppmin_f32_<0x111>(x);
    x = dppmin_f32_<0x112>(x);
    x = dppmin_f32_<0x114>(x);
    x = dppmin_f32_<0x118>(x);
    x = dppmin_f32_<0x142>(x);
    x = dppmin_f32_<0x143>(x);
    return __int_as_float(__builtin_amdgcn_readlane(__float_as_int(x), 63));
}
template<int CTRL>
__device__ __forceinline__ unsigned dppmin_u32_(unsigned x) {
    const unsigned moved = (unsigned)__builtin_amdgcn_update_dpp(
        (int)0xFFFFFFFFu, (int)x, CTRL, 0xF, 0xF, false);
    return x < moved ? x : moved;
}
__device__ __forceinline__ unsigned wave_min_u32_(unsigned x) {
    x = dppmin_u32_<0x111>(x);
    x = dppmin_u32_<0x112>(x);
    x = dppmin_u32_<0x114>(x);
    x = dppmin_u32_<0x118>(x);
    x = dppmin_u32_<0x142>(x);
    x = dppmin_u32_<0x143>(x);
    return (unsigned)__builtin_amdgcn_readlane((int)x, 63);
}

// ---------------------------------------------------------------------------
// Phase 2: exact successive-shortest-path LAP (same unique optimum as the
// reference's LAPJV). One block = one batch, ONE wave. Strided ownership:
// lane L owns cols {L, L+64, ...} (proven lowest-conflict layout, R3).
//
// Hot loop, minimized issue count (~4 VALU ops/col):
//   - no rem mask / no clamp: popped col k* is poisoned on its owner lane:
//       shortfin[k*]=short[k*]; short[k*]=+INF (can't win argmin);
//       vwork[k*]=-INF (t=a-vwork=+INF => r=+INF, can't re-enter).
//     v_r stays pristine for dual updates.
//   - t_r[k]=a-vwork[k] precomputed in the load shadow; relax is
//     r=cv+t; cmp; min; cndmask(path).
//   - local min = 7 fminf (bit-exact); tree1 = 6 fused v_min_f32_dpp;
//     payload select by equality (k ascending => lowest j, np.argmin);
//     tree2 = 6 fused v_min_u32_dpp over (j<<10)|(row4col[j]+1) payload
//     (registers, refreshed per augment) => winner col AND next row with
//     ZERO multi-address LDS in the chain. Broadcast u_lds[i] read hides
//     under the 8 coalesced row loads.
// ---------------------------------------------------------------------------
__global__ __launch_bounds__(64) void lsa_kernel(
    const float* __restrict__ cost, const float* __restrict__ v0,
    const int* __restrict__ amin, int* __restrict__ mapping)
{
    constexpr int n = Nq;  // 500
    __shared__ float u_lds[512];
    __shared__ float shortest_lds[512];
    __shared__ int   path_lds[512];
    __shared__ int   row4col_lds[512];
    __shared__ int   col4row_lds[512];

    const int lane = threadIdx.x;
    const int b = blockIdx.x;
    const float* __restrict__ cb = cost + (size_t)b * n * n;

    const unsigned init_mask = (lane < (n & 63)) ? 0xFFu : 0x7Fu;  // k=7 valid iff lane<52

    float v_r[8], vwork_r[8], short_r[8], shortfin_r[8], t_r[8];
    int path_r[8];
    unsigned pay_r[8];   // (j<<10) | (row4col[j]+1)

    // --- init: duals from column reduction, greedy matching on tight edges ---
    #pragma unroll
    for (int k = 0; k < 8; ++k) {
        const int j = lane + (k << 6);
        const bool valid = (init_mask >> k) & 1;
        v_r[k] = valid ? v0[b * n + j] : 0.0f;
        vwork_r[k] = valid ? v_r[k] : -INFINITY;   // invalid cols: r=+INF forever
        short_r[k] = INFINITY;
        shortfin_r[k] = INFINITY;
        path_r[k] = -1;
    }
    for (int t = lane; t < n; t += 64)
        path_lds[t] = amin[b * n + t];            // stash argmins for lane0
    for (int t = lane; t < 512; t += 64) {
        u_lds[t] = 0.0f; row4col_lds[t] = -1; col4row_lds[t] = -1;
    }
    __syncthreads();
    if (lane == 0) {
        for (int j = 0; j < n; ++j) {
            const int i0 = path_lds[j];
            if (col4row_lds[i0] < 0) { col4row_lds[i0] = j; row4col_lds[j] = i0; }
        }
    }
    __syncthreads();
    #pragma unroll
    for (int k = 0; k < 8; ++k) {
        const int j = lane + (k << 6);
        const bool valid = (init_mask >> k) & 1;
        pay_r[k] = valid ? (((unsigned)j << 10) | (unsigned)(row4col_lds[j] + 1))
                         : 0xFFFFFFFFu;
    }
    for (int t = lane; t < n; t += 64)
        path_lds[t] = -1;
    unsigned sr_mask = 0;
    __syncthreads();

    // --- successive shortest paths over free rows ---
    for (int cur_row = 0; cur_row < n; ++cur_row) {
        if (col4row_lds[cur_row] >= 0) continue;   // wave-uniform

        int sink_j = -1;
        int i = cur_row;
        float min_val = 0.0f;
        float a = -u_lds[cur_row];                  // a = min_val - u[i]
        const float* __restrict__ crow = cb + (size_t)i * n;

        for (int pops = 0; pops < n; ++pops) {
            if ((i & 63) == lane) sr_mask |= 1u << (i >> 6);

            // 8 coalesced row loads (strided); t_r fills the load shadow
            float cv[8];
            #pragma unroll
            for (int k = 0; k < 8; ++k) {
                const int j = lane + (k << 6);
                cv[k] = crow[j < n ? j : 0];
            }
            #pragma unroll
            for (int k = 0; k < 8; ++k) t_r[k] = a - vwork_r[k];

            // relax: 4 ops/col
            #pragma unroll
            for (int k = 0; k < 8; ++k) {
                const float r = cv[k] + t_r[k];
                if (r < short_r[k]) { short_r[k] = r; path_r[k] = i; }
            }

            // local min (bit-exact), wave min, payload select, payload tree
            const float lmin = fminf(
                fminf(fminf(short_r[0], short_r[1]), fminf(short_r[2], short_r[3])),
                fminf(fminf(short_r[4], short_r[5]), fminf(short_r[6], short_r[7])));
            const float gmin = wave_min_f32_(lmin);

            unsigned sel = 0xFFFFFFFFu;
            #pragma unroll
            for (int k = 7; k >= 0; --k)          // k ascending priority -> lowest j
                if (short_r[k] == gmin) sel = pay_r[k];
            const unsigned win = wave_min_u32_(sel);

            min_val = gmin;
            const unsigned jst = win >> 10;
            const unsigned rc1 = win & 0x3FFu;

            // pop bookkeeping: poison winner col on its owner lane (uniform k)
            const int owner = (int)(jst & 63u);
            const int kwin = (int)(jst >> 6);
            #pragma unroll
            for (int k = 0; k < 8; ++k) {
                if (k == kwin && lane == owner) {
                    shortfin_r[k] = short_r[k];
                    short_r[k] = INFINITY;
                    vwork_r[k] = -INFINITY;
                }
            }

            if (rc1 == 0u) { sink_j = (int)jst; break; }
            i = (int)rc1 - 1;
            crow = cb + (size_t)i * n;
            a = min_val - u_lds[i];   // broadcast LDS read, hides under row loads
        }

        if (sink_j >= 0) {
            // publish final labels/path (only scanned cols are ever read)
            #pragma unroll
            for (int k = 0; k < 8; ++k) {
                const int j = lane + (k << 6);
                if (j < n) {
                    shortest_lds[j] = shortfin_r[k];
                    path_lds[j] = path_r[k];
                }
            }
            __syncthreads();

            // u-update for SR rows (col4row read BEFORE augmentation);
            // v-update for scanned cols (marker: vwork == -INF), register-local
            #pragma unroll
            for (int k = 0; k < 8; ++k) {
                const int t = lane + (k << 6);
                if (t < n && (sr_mask & (1u << k))) {
                    if (t == cur_row) u_lds[t] += min_val;
                    else              u_lds[t] += min_val - shortest_lds[col4row_lds[t]];
                }
            }
            #pragma unroll
            for (int k = 0; k < 8; ++k) {
                if (((init_mask >> k) & 1) && vwork_r[k] == -INFINITY)
                    v_r[k] -= min_val - shortfin_r[k];
            }
            __syncthreads();

            if (lane == 0) {   // augment alternating path
                int j = sink_j;
                for (;;) {
                    const int ii = path_lds[j];
                    row4col_lds[j] = ii;
                    const int tmp = col4row_lds[ii];
                    col4row_lds[ii] = j;
                    j = tmp;
                    if (ii == cur_row) break;
                }
            }
            __syncthreads();
        }

        // refresh payloads (strided LDS reads, 2-way alias = free) and
        // reset per-row register state
        #pragma unroll
        for (int k = 0; k < 8; ++k) {
            const int j = lane + (k << 6);
            const bool valid = (init_mask >> k) & 1;
            pay_r[k] = valid ? (((unsigned)j << 10) | (unsigned)(row4col_lds[j] + 1))
                             : 0xFFFFFFFFu;
            vwork_r[k] = valid ? v_r[k] : -INFINITY;
            short_r[k] = INFINITY;
            shortfin_r[k] = INFINITY;
            path_r[k] = -1;
        }
        sr_mask = 0;
        __syncthreads();
    }

    for (int t = lane; t < n; t += 64)
        mapping[b * n + t] = col4row_lds[t];
}

// ---------------------------------------------------------------------------
// Phase 3: extrapolation (square problem => every row assigned; -1 guarded).
// ---------------------------------------------------------------------------
__global__ __launch_bounds__(256) void extrap_boxes_kernel(
    const float* __restrict__ p1_boxes, const float* __restrict__ p2_boxes,
    const float* __restrict__ toffs, const int* __restrict__ mapping,
    float* __restrict__ out_boxes)
{
    const int idx = blockIdx.x * blockDim.x + threadIdx.x;  // b*Mq + i
    if (idx >= Bq * Mq) return;
    const int b = idx / Mq;
    const float t0 = toffs[b * 3 + 0], t1 = toffs[b * 3 + 1], t2 = toffs[b * 3 + 2];
    const float factor = (t2 - t1) / (t1 - t0);
    const int m = mapping[idx];
    const float4 p2 = ((const float4*)p2_boxes)[idx];
    const float4 p1 = (m >= 0) ? ((const float4*)p1_boxes)[b * Nq + m] : p2;
    float4 o;
    o.x = p2.x + (p2.x - p1.x) * factor;
    o.y = p2.y + (p2.y - p1.y) * factor;
    o.z = fmaxf(p2.z + (p2.z - p1.z) * factor, 0.0f);
    o.w = fmaxf(p2.w + (p2.w - p1.w) * factor, 0.0f);
    ((float4*)out_boxes)[idx] = o;
}

__global__ __launch_bounds__(256) void extrap_logits_kernel(
    const float* __restrict__ p1_logits, const float* __restrict__ p2_logits,
    const int* __restrict__ mapping, float* __restrict__ out_logits)
{
    const int idx = blockIdx.x * blockDim.x + threadIdx.x;  // (b*Mq + i)*Cq + c
    if (idx >= Bq * Mq * Cq) return;
    const int c = idx % Cq;
    const int bi = idx / Cq;
    const int b = bi / Mq;
    const int m = mapping[bi];
    const float corr = (m >= 0) ? p1_logits[((size_t)b * Nq + m) * Cq + c] : 0.0f;
    out_logits[idx] = 0.5f * (p2_logits[idx] + corr);
}

// ---------------------------------------------------------------------------
extern "C" void kernel_launch(void* const* d_in, const int* in_sizes, int n_in,
                              void* d_out, int out_size, void* d_ws, size_t ws_size,
                              hipStream_t stream) {
    const float* p1_boxes  = (const float*)d_in[0];  // (B,N,4)
    const float* p1_logits = (const float*)d_in[1];  // (B,N,C)
    const float* p2_boxes  = (const float*)d_in[2];  // (B,M,4)
    const float* p2_logits = (const float*)d_in[3];  // (B,M,C)
    const float* toffs     = (const float*)d_in[4];  // (B,3)
    float* out = (float*)d_out;                      // boxes3 ++ logits3

    char* ws = (char*)d_ws;
    float* cost    = (float*)ws;                                   // 4 MB
    int*   mapping = (int*)  (ws + 4000000);                       // 8 KB
    float* v0      = (float*)(ws + 4008000);                       // 8 KB
    int*   amin    = (int*)  (ws + 4016000);                       // 8 KB

    dim3 cgrid((Nq + 15) / 16, (Mq + 15) / 16, Bq);
    cost_kernel<<<cgrid, 256, 0, stream>>>(p1_boxes, p1_logits, p2_boxes, p2_logits, cost);

    colred_kernel<<<dim3(2, Bq), 256, 0, stream>>>(cost, v0, amin);

    lsa_kernel<<<Bq, 64, 0, stream>>>(cost, v0, amin, mapping);

    extrap_boxes_kernel<<<(Bq * Mq + 255) / 256, 256, 0, stream>>>(
        p1_boxes, p2_boxes, toffs, mapping, out);
    extrap_logits_kernel<<<(Bq * Mq * Cq + 255) / 256, 256, 0, stream>>>(
        p1_logits, p2_logits, mapping, out + Bq * Mq * 4);
}